// Round 7
// baseline (19481.721 us; speedup 1.0000x reference)
//
#include <hip/hip_runtime.h>
#include <hip/hip_bf16.h>

typedef __hip_bfloat16 bf16;

__device__ __forceinline__ float lrelu(float x) { return x > 0.f ? x : 0.01f * x; }

__device__ __forceinline__ float ldv(float v) { return v; }
__device__ __forceinline__ float ldv(bf16 v) { return __bfloat162float(v); }
__device__ __forceinline__ void stv(float* p, float v) { *p = v; }
__device__ __forceinline__ void stv(bf16* p, float v) { *p = __float2bfloat16(v); }

// per-array dtype-dispatched float read: isbf=1 -> bf16, else fp32
__device__ __forceinline__ float in_rd(const void* p, size_t i, int isbf) {
  return isbf ? __bfloat162float(((const bf16*)p)[i]) : ((const float*)p)[i];
}
// per-array int read: is64=1 -> int64, else int32
__device__ __forceinline__ int ix_rd(const void* p, size_t i, int is64) {
  return is64 ? (int)((const long long*)p)[i] : ((const int*)p)[i];
}

// ---------------- per-array format probe ----------------
__global__ void detect_probe(const unsigned int* __restrict__ w, int s, int mode,
                             int* __restrict__ flag) {
  __shared__ int sh[256];
  int t = threadIdx.x;
  int c = 0;
  if (t < s) {
    if (mode == 0) {
      unsigned int v = w[t];
      int e = (v >> 7) & 0xFF;
      c = (e >= 100 && e <= 140) ? 1 : 0;
    } else {
      c = (w[2 * t + 1] == 0u) ? 1 : 0;
    }
  }
  sh[t] = c;
  __syncthreads();
  for (int d = 128; d; d >>= 1) {
    if (t < d) sh[t] += sh[t + d];
    __syncthreads();
  }
  if (t == 0) flag[0] = (mode == 0) ? (sh[0] * 10 >= 7 * s) : (sh[0] * 10 >= 9 * s);
}

__global__ void inherit_flag(int* __restrict__ flags, int dst, int src) {
  if (threadIdx.x == 0) flags[dst] = flags[src];
}

// ---------------- utilities ----------------
__global__ void sig_fill(float* __restrict__ p, int n, float v) {
  int i = blockIdx.x * 256 + threadIdx.x;
  if (i < n) p[i] = v;
}
__global__ void zero_ints(int* __restrict__ p, int n) {
  int i = blockIdx.x * 256 + threadIdx.x;
  if (i < n) p[i] = 0;
}

// ---------------- CSR build ----------------
__global__ void count_edges(const void* __restrict__ ei, const void* __restrict__ et,
                            const int* __restrict__ fl, int* __restrict__ cnt, int NEr,
                            int NNr) {
  int e = blockIdx.x * 256 + threadIdx.x;
  if (e >= NEr) return;
  int d = ix_rd(ei, (size_t)NEr + e, fl[4]);
  int r = ix_rd(et, e, fl[5]) & 1;
  if ((unsigned)d >= (unsigned)NNr) return;
  atomicAdd(&cnt[r * NNr + d], 1);
}

// exclusive scan in 1024-element blocks
__global__ void scan_blocks(const int* __restrict__ in, int* __restrict__ out,
                            int* __restrict__ bsum, int n) {
  __shared__ int sh[256];
  int t = threadIdx.x;
  int base = blockIdx.x * 1024 + t * 4;
  int a[4];
  int s = 0;
#pragma unroll
  for (int i = 0; i < 4; i++) {
    a[i] = (base + i < n) ? in[base + i] : 0;
    s += a[i];
  }
  sh[t] = s;
  __syncthreads();
  for (int d = 1; d < 256; d <<= 1) {
    int v = (t >= d) ? sh[t - d] : 0;
    __syncthreads();
    sh[t] += v;
    __syncthreads();
  }
  int ex = sh[t] - s;
#pragma unroll
  for (int i = 0; i < 4; i++) {
    if (base + i < n) out[base + i] = ex;
    ex += a[i];
  }
  if (t == 255 && bsum) bsum[blockIdx.x] = sh[255];
}

__global__ void scan_add_inv(int* __restrict__ off, const int* __restrict__ bsumsc,
                             const int* __restrict__ cnt, float* __restrict__ inv, int n) {
  int i = blockIdx.x * 256 + threadIdx.x;
  if (i >= n) return;
  off[i] += bsumsc[i >> 10];
  inv[i] = 1.f / fmaxf((float)cnt[i], 1.f);
}

__global__ void fill_elist(const void* __restrict__ ei, const void* __restrict__ et,
                           const int* __restrict__ fl, const int* __restrict__ off,
                           int* __restrict__ fill, int* __restrict__ elist, int NEr, int NNr) {
  int e = blockIdx.x * 256 + threadIdx.x;
  if (e >= NEr) return;
  int s = ix_rd(ei, e, fl[4]);
  int d = ix_rd(ei, (size_t)NEr + e, fl[4]);
  int r = ix_rd(et, e, fl[5]) & 1;
  if ((unsigned)d >= (unsigned)NNr || (unsigned)s >= (unsigned)NNr) return;
  int idx = r * NNr + d;
  int slot = off[idx] + atomicAdd(&fill[idx], 1);
  elist[slot] = s;
}

// ---------------- encoders ----------------
template <typename T>
__global__ void encode_users(const void* __restrict__ des, const void* __restrict__ nump,
                             const void* __restrict__ catp, const void* __restrict__ Wd,
                             const void* __restrict__ bd, const void* __restrict__ Wn,
                             const void* __restrict__ bn, const void* __restrict__ Wc,
                             const void* __restrict__ bc, const int* __restrict__ fl,
                             T* __restrict__ x, int NUr, int dDes, int dNum, int dCat) {
  int t = threadIdx.x;
  int u = blockIdx.x * 2 + (t >> 7);
  int j = t & 127;
  if (u >= NUr) return;
  float acc;
  if (j < 64) {
    acc = in_rd(bd, j, fl[7]);
    for (int k = 0; k < dDes; k++)
      acc += in_rd(des, (size_t)u * dDes + k, fl[0]) * in_rd(Wd, (size_t)j * dDes + k, fl[6]);
  } else if (j < 96) {
    int jj = j - 64;
    acc = in_rd(bn, jj, fl[9]);
    for (int k = 0; k < dNum; k++)
      acc += in_rd(nump, (size_t)u * dNum + k, fl[2]) * in_rd(Wn, (size_t)jj * dNum + k, fl[8]);
  } else {
    int jj = j - 96;
    acc = in_rd(bc, jj, fl[11]);
    for (int k = 0; k < dCat; k++)
      acc += in_rd(catp, (size_t)u * dCat + k, fl[3]) * in_rd(Wc, (size_t)jj * dCat + k, fl[10]);
  }
  stv(&x[(size_t)u * 128 + j], lrelu(acc));
}

template <typename T>
__global__ void encode_tweets(const void* __restrict__ tw, const void* __restrict__ Wt,
                              const void* __restrict__ bt, const int* __restrict__ fl,
                              T* __restrict__ x, int NUr, int NTr, int dTw) {
  int t = threadIdx.x;
  int u = blockIdx.x * 2 + (t >> 7);
  int j = t & 127;
  if (u >= NTr) return;
  float acc = in_rd(bt, j, fl[13]);
  for (int k = 0; k < dTw; k++)
    acc += in_rd(tw, (size_t)u * dTw + k, fl[1]) * in_rd(Wt, (size_t)j * dTw + k, fl[12]);
  stv(&x[(size_t)(NUr + u) * 128 + j], lrelu(acc));
}

// ---------------- row GEMM (torch layout W [128,128]) + lrelu ----------------
template <typename T>
__global__ void gemm_lin(const T* __restrict__ A, const void* __restrict__ W,
                         const void* __restrict__ B, const int* __restrict__ fl, int wi,
                         int bi, T* __restrict__ Out) {
  int row = blockIdx.x, o = threadIdx.x;
  __shared__ float xs[128];
  xs[o] = ldv(A[(size_t)row * 128 + o]);
  __syncthreads();
  int fw = fl[wi], fb = fl[bi];
  float acc = in_rd(B, o, fb);
  for (int k = 0; k < 128; k++) acc += xs[k] * in_rd(W, (size_t)o * 128 + k, fw);
  stv(&Out[(size_t)row * 128 + o], lrelu(acc));
}

// ---------------- fused RGCN conv, one row per block, single store ----------------
// Out[row,:] = X[row,:]@root + mean0@rw[0] + mean1@rw[1] + bias  (all math [k,n] layout)
template <typename T>
__global__ void conv_row(const T* __restrict__ X, const int* __restrict__ off,
                         const int* __restrict__ cnt, const int* __restrict__ elist,
                         const float* __restrict__ inv, const void* __restrict__ root,
                         const void* __restrict__ rw, const void* __restrict__ bias,
                         const int* __restrict__ fl, T* __restrict__ Out, int NNr) {
  int row = blockIdx.x, o = threadIdx.x;
  __shared__ float xs[128], ms[128];
  xs[o] = ldv(X[(size_t)row * 128 + o]);
  __syncthreads();
  int fw = fl[17], fr = fl[16], fb = fl[18];
  float acc = in_rd(bias, o, fb);
  for (int k = 0; k < 128; k++) acc += xs[k] * in_rd(root, (size_t)k * 128 + o, fw);
  for (int r = 0; r < 2; r++) {
    int idx = r * NNr + row;
    int st = off[idx];
    int n = cnt[idx];
    float s = 0.f;
    for (int e = 0; e < n; e++) {
      int src = elist[st + e];
      s += ldv(X[(size_t)src * 128 + o]);  // coalesced across threads
    }
    __syncthreads();  // previous ms fully consumed
    ms[o] = s * inv[idx];
    __syncthreads();
    size_t wb = (size_t)r * 16384;
    for (int k = 0; k < 128; k++) acc += ms[k] * in_rd(rw, wb + (size_t)k * 128 + o, fr);
  }
  stv(&Out[(size_t)row * 128 + o], acc);
}

// ---------------- final 128 -> 2 linear, FP32 out ----------------
template <typename T>
__global__ void out_linear(const T* __restrict__ x, const void* __restrict__ W,
                           const void* __restrict__ B, const int* __restrict__ fl,
                           float* __restrict__ out, int NNr) {
  int wave = threadIdx.x >> 6;
  int lane = threadIdx.x & 63;
  int i = blockIdx.x * 4 + wave;
  if (i >= NNr) return;
  int fw = fl[21], fb = fl[22];
  const T* xr = x + (size_t)i * 128;
  float x0 = ldv(xr[lane]);
  float x1 = ldv(xr[lane + 64]);
  float p0 = x0 * in_rd(W, lane, fw) + x1 * in_rd(W, lane + 64, fw);
  float p1 = x0 * in_rd(W, 128 + lane, fw) + x1 * in_rd(W, 128 + lane + 64, fw);
#pragma unroll
  for (int offs = 32; offs; offs >>= 1) {
    p0 += __shfl_down(p0, offs, 64);
    p1 += __shfl_down(p1, offs, 64);
  }
  if (lane == 0) {
    out[(size_t)i * 2] = p0 + in_rd(B, 0, fb);
    out[(size_t)i * 2 + 1] = p1 + in_rd(B, 1, fb);
  }
}

// ---------------- pipeline ----------------
template <typename T>
static void run_pipeline(void* const* d_in, const int* S, float* out, char* ws,
                         int NUr, int NTr, int NEr, int dDes, int dNum, int dCat, int dTw,
                         hipStream_t stream) {
  const int NNr = NUr + NTr;
  const size_t xbytes = (size_t)NNr * 128 * sizeof(T);
  T* xa = (T*)ws;
  T* xb = (T*)(ws + xbytes);
  char* p = ws + 2 * xbytes;
  int* cnt = (int*)p;     p += (size_t)2 * NNr * 4;
  int* fill = (int*)p;    p += (size_t)2 * NNr * 4;  // contiguous with cnt
  int* off = (int*)p;     p += (size_t)2 * NNr * 4;
  int* bsum = (int*)p;    p += 2048 * 4;
  int* bsumsc = (int*)p;  p += 2048 * 4;
  float* inv = (float*)p; p += (size_t)2 * NNr * 4;
  int* elist = (int*)p;   p += (size_t)NEr * 4;
  int* flags = (int*)p;

  // per-array dtype detection (float arrays mode 0)
  const int fidx[20] = {0, 1, 2, 3, 6, 7, 8, 9, 10, 11, 12, 13, 14, 15, 16, 17, 18, 19, 20, 21};
  for (int q = 0; q < 20; q++) {
    int i = fidx[q];
    int s = S[i] / 2;
    if (s > 256) s = 256;
    if (s < 1) s = 1;
    detect_probe<<<1, 256, 0, stream>>>((const unsigned int*)d_in[i], s, 0, flags + i);
  }
  inherit_flag<<<1, 64, 0, stream>>>(flags, 22, 21);  // b_o2 inherits W_o2
  {
    int s = NEr < 256 ? NEr : 256;
    detect_probe<<<1, 256, 0, stream>>>((const unsigned int*)d_in[4], s, 1, flags + 4);
    int s2 = NEr / 2 < 256 ? NEr / 2 : 256;
    if (s2 < 1) s2 = 1;
    detect_probe<<<1, 256, 0, stream>>>((const unsigned int*)d_in[5], s2, 1, flags + 5);
  }

  const void* ei = d_in[4];
  const void* et = d_in[5];
  const int nb1 = (2 * NNr + 1023) / 1024;

  // CSR build (shared by both convs)
  zero_ints<<<(4 * NNr + 255) / 256, 256, 0, stream>>>(cnt, 4 * NNr);  // cnt + fill
  zero_ints<<<16, 256, 0, stream>>>(bsum, 4096);                       // bsum + bsumsc
  count_edges<<<(NEr + 255) / 256, 256, 0, stream>>>(ei, et, flags, cnt, NEr, NNr);
  scan_blocks<<<nb1, 256, 0, stream>>>(cnt, off, bsum, 2 * NNr);
  scan_blocks<<<1, 256, 0, stream>>>(bsum, bsumsc, nullptr, nb1);
  scan_add_inv<<<(2 * NNr + 255) / 256, 256, 0, stream>>>(off, bsumsc, cnt, inv, 2 * NNr);
  fill_elist<<<(NEr + 255) / 256, 256, 0, stream>>>(ei, et, flags, off, fill, elist, NEr, NNr);

  // encoders -> xa
  encode_users<T><<<(NUr + 1) / 2, 256, 0, stream>>>(d_in[0], d_in[2], d_in[3], d_in[6],
                                                     d_in[7], d_in[8], d_in[9], d_in[10],
                                                     d_in[11], flags, xa, NUr, dDes, dNum, dCat);
  encode_tweets<T><<<(NTr + 1) / 2, 256, 0, stream>>>(d_in[1], d_in[12], d_in[13], flags, xa,
                                                      NUr, NTr, dTw);

  // x = lrelu(x @ W_in^T + b_in): xa -> xb
  gemm_lin<T><<<NNr, 128, 0, stream>>>(xa, d_in[14], d_in[15], flags, 14, 15, xb);

  // conv1: xb -> xa ; conv2: xa -> xb
  conv_row<T><<<NNr, 128, 0, stream>>>(xb, off, cnt, elist, inv, d_in[17], d_in[16], d_in[18],
                                       flags, xa, NNr);
  conv_row<T><<<NNr, 128, 0, stream>>>(xa, off, cnt, elist, inv, d_in[17], d_in[16], d_in[18],
                                       flags, xb, NNr);

  // x = lrelu(x @ W_o1^T + b_o1): xb -> xa
  gemm_lin<T><<<NNr, 128, 0, stream>>>(xb, d_in[19], d_in[20], flags, 19, 20, xa);

  // out = x @ W_o2^T + b_o2  (FP32 output)
  out_linear<T><<<(NNr + 3) / 4, 256, 0, stream>>>(xa, d_in[21], d_in[22], flags, out, NNr);
}

extern "C" void kernel_launch(void* const* d_in, const int* in_sizes, int n_in,
                              void* d_out, int out_size, void* d_ws, size_t ws_size,
                              hipStream_t stream) {
  float* out = (float*)d_out;
  char* ws = (char*)d_ws;

  auto signal = [&](int k) {
    sig_fill<<<(out_size + 255) / 256, 256, 0, stream>>>(out, out_size, (float)(200 + k));
  };

  if (n_in != 23) { signal(1); return; }
  const int* S = in_sizes;
  if (S[7] != 64 || S[9] != 32 || S[11] != 32 || S[13] != 128) { signal(2); return; }
  if (S[15] != 128) { signal(3); return; }
  if (S[6] % 64 || S[8] % 32 || S[10] % 32 || S[12] % 128) { signal(4); return; }
  int dDes = S[6] / 64, dNum = S[8] / 32, dCat = S[10] / 32, dTw = S[12] / 128;
  if (dDes <= 0 || dTw <= 0 || S[0] % dDes || S[1] % dTw) { signal(5); return; }
  int NUr = S[0] / dDes, NTr = S[1] / dTw, NNr = NUr + NTr, NEr = S[5];
  if (S[2] != NUr * dNum || S[3] != NUr * dCat) { signal(5); return; }
  if (S[4] != 2 * NEr || NEr < 1024) { signal(6); return; }
  if (S[14] != 16384 || S[16] != 32768 || S[17] != 16384 || S[18] != 128 ||
      S[19] != 16384 || S[20] != 128 || S[21] != 256 || S[22] != 2) { signal(7); return; }
  if (out_size != NNr * 2) { signal(8); return; }

  const size_t smallBytes =
      (size_t)4 * ((size_t)2 * NNr * 4) + 2 * 2048 * 4 + (size_t)NEr * 4 + 256;
  const size_t needF32 = 2 * (size_t)NNr * 128 * 4 + smallBytes;   // ~213.4 MB
  const size_t needB16 = 2 * (size_t)NNr * 128 * 2 + smallBytes;   // ~111 MB

  if (ws_size >= needF32) {
    run_pipeline<float>(d_in, S, out, ws, NUr, NTr, NEr, dDes, dNum, dCat, dTw, stream);
  } else if (ws_size >= needB16) {
    run_pipeline<bf16>(d_in, S, out, ws, NUr, NTr, NEr, dDes, dNum, dCat, dTw, stream);
  } else {
    signal(9);
  }
}

// Round 8
// 4141.151 us; speedup vs baseline: 4.7044x; 4.7044x over previous
//
#include <hip/hip_runtime.h>
#include <hip/hip_bf16.h>

typedef __hip_bfloat16 bf16;

#define BK 32
#define LDA 132  // padded LDS leading dim for 128-wide tiles

__device__ __forceinline__ float lrelu(float x) { return x > 0.f ? x : 0.01f * x; }

__device__ __forceinline__ float ldv(float v) { return v; }
__device__ __forceinline__ float ldv(bf16 v) { return __bfloat162float(v); }
__device__ __forceinline__ void stv(float* p, float v) { *p = v; }
__device__ __forceinline__ void stv(bf16* p, float v) { *p = __float2bfloat16(v); }

// per-array dtype-dispatched float read: isbf=1 -> bf16, else fp32
__device__ __forceinline__ float in_rd(const void* p, size_t i, int isbf) {
  return isbf ? __bfloat162float(((const bf16*)p)[i]) : ((const float*)p)[i];
}
// per-array int read: is64=1 -> int64, else int32
__device__ __forceinline__ int ix_rd(const void* p, size_t i, int is64) {
  return is64 ? (int)((const long long*)p)[i] : ((const int*)p)[i];
}

// ---------------- per-array format probe ----------------
__global__ void detect_probe(const unsigned int* __restrict__ w, int s, int mode,
                             int* __restrict__ flag) {
  __shared__ int sh[256];
  int t = threadIdx.x;
  int c = 0;
  if (t < s) {
    if (mode == 0) {
      unsigned int v = w[t];
      int e = (v >> 7) & 0xFF;
      c = (e >= 100 && e <= 140) ? 1 : 0;
    } else {
      c = (w[2 * t + 1] == 0u) ? 1 : 0;
    }
  }
  sh[t] = c;
  __syncthreads();
  for (int d = 128; d; d >>= 1) {
    if (t < d) sh[t] += sh[t + d];
    __syncthreads();
  }
  if (t == 0) flag[0] = (mode == 0) ? (sh[0] * 10 >= 7 * s) : (sh[0] * 10 >= 9 * s);
}

__global__ void inherit_flag(int* __restrict__ flags, int dst, int src) {
  if (threadIdx.x == 0) flags[dst] = flags[src];
}

// ---------------- utilities ----------------
__global__ void sig_fill(float* __restrict__ p, int n, float v) {
  int i = blockIdx.x * 256 + threadIdx.x;
  if (i < n) p[i] = v;
}
__global__ void zero_ints(int* __restrict__ p, int n) {
  int i = blockIdx.x * 256 + threadIdx.x;
  if (i < n) p[i] = 0;
}

// ---------------- CSR build ----------------
__global__ void count_edges(const void* __restrict__ ei, const void* __restrict__ et,
                            const int* __restrict__ fl, int* __restrict__ cnt, int NEr,
                            int NNr) {
  int e = blockIdx.x * 256 + threadIdx.x;
  if (e >= NEr) return;
  int d = ix_rd(ei, (size_t)NEr + e, fl[4]);
  int r = ix_rd(et, e, fl[5]) & 1;
  if ((unsigned)d >= (unsigned)NNr) return;
  atomicAdd(&cnt[r * NNr + d], 1);
}

__global__ void scan_blocks(const int* __restrict__ in, int* __restrict__ out,
                            int* __restrict__ bsum, int n) {
  __shared__ int sh[256];
  int t = threadIdx.x;
  int base = blockIdx.x * 1024 + t * 4;
  int a[4];
  int s = 0;
#pragma unroll
  for (int i = 0; i < 4; i++) {
    a[i] = (base + i < n) ? in[base + i] : 0;
    s += a[i];
  }
  sh[t] = s;
  __syncthreads();
  for (int d = 1; d < 256; d <<= 1) {
    int v = (t >= d) ? sh[t - d] : 0;
    __syncthreads();
    sh[t] += v;
    __syncthreads();
  }
  int ex = sh[t] - s;
#pragma unroll
  for (int i = 0; i < 4; i++) {
    if (base + i < n) out[base + i] = ex;
    ex += a[i];
  }
  if (t == 255 && bsum) bsum[blockIdx.x] = sh[255];
}

__global__ void scan_add_inv(int* __restrict__ off, const int* __restrict__ bsumsc,
                             const int* __restrict__ cnt, float* __restrict__ inv, int n) {
  int i = blockIdx.x * 256 + threadIdx.x;
  if (i >= n) return;
  off[i] += bsumsc[i >> 10];
  inv[i] = 1.f / fmaxf((float)cnt[i], 1.f);
}

__global__ void fill_elist(const void* __restrict__ ei, const void* __restrict__ et,
                           const int* __restrict__ fl, const int* __restrict__ off,
                           int* __restrict__ fill, int* __restrict__ elist, int NEr, int NNr) {
  int e = blockIdx.x * 256 + threadIdx.x;
  if (e >= NEr) return;
  int s = ix_rd(ei, e, fl[4]);
  int d = ix_rd(ei, (size_t)NEr + e, fl[4]);
  int r = ix_rd(et, e, fl[5]) & 1;
  if ((unsigned)d >= (unsigned)NNr || (unsigned)s >= (unsigned)NNr) return;
  int idx = r * NNr + d;
  int slot = off[idx] + atomicAdd(&fill[idx], 1);
  elist[slot] = s;
}

// ---------------- encoder GEMM: x[(row0+i)*128+col0+j] = lrelu(A[i,:K]@W[j,:K]^T + b[j]) ----
// W (torch [N,K]) staged in LDS with odd stride (conflict-free); A read direct (wave-broadcast).
// N in {32,64,128} (divides 256), K <= 101. 64 rows per block.
template <typename T>
__global__ __launch_bounds__(256) void enc_gemm(const void* __restrict__ A,
                                                const void* __restrict__ W,
                                                const void* __restrict__ B,
                                                const int* __restrict__ fl, int fa, int fw,
                                                int fb, T* __restrict__ x, int M, int K, int N,
                                                int row0, int col0) {
  __shared__ float Wb[128 * 102];
  __shared__ float bb[128];
  int t = threadIdx.x;
  int stride = (K & 1) ? K : K + 1;
  int fA = fl[fa];
  {
    int fW = fl[fw], fB = fl[fb];
    for (int idx = t; idx < N * K; idx += 256) {
      int j = idx / K, k = idx - j * K;
      Wb[j * stride + k] = in_rd(W, (size_t)j * K + k, fW);
    }
    if (t < N) bb[t] = in_rd(B, t, fB);
  }
  __syncthreads();
  int j = t % N;
  int r = t / N;
  int R = 256 / N;
  int iEnd = blockIdx.x * 64 + 64;
  if (iEnd > M) iEnd = M;
  const float* wrow = &Wb[j * stride];
  if (!fA) {
    const float* Af = (const float*)A;
    for (int i = blockIdx.x * 64 + r; i < iEnd; i += R) {
      const float* a = Af + (size_t)i * K;
      float acc = bb[j];
      for (int k = 0; k < K; k++) acc += a[k] * wrow[k];
      stv(&x[(size_t)(row0 + i) * 128 + col0 + j], lrelu(acc));
    }
  } else {
    const bf16* Ab = (const bf16*)A;
    for (int i = blockIdx.x * 64 + r; i < iEnd; i += R) {
      const bf16* a = Ab + (size_t)i * K;
      float acc = bb[j];
      for (int k = 0; k < K; k++) acc += __bfloat162float(a[k]) * wrow[k];
      stv(&x[(size_t)(row0 + i) * 128 + col0 + j], lrelu(acc));
    }
  }
}

// ---------------- tiled K=128 GEMM, torch-layout W [128,128], +bias, lrelu ----------------
template <typename T>
__global__ __launch_bounds__(256, 2) void gemm_k128(const T* __restrict__ A,
                                                    const void* __restrict__ W,
                                                    const void* __restrict__ bias,
                                                    const int* __restrict__ fl, int wi, int bi,
                                                    T* __restrict__ Out, int M) {
  const int fw = fl[wi], fb = fl[bi];
  __shared__ float As[BK][LDA];
  __shared__ float Bs[BK][LDA];
  int t = threadIdx.x;
  int i0 = blockIdx.x * 128;
  float acc[8][8] = {};
  for (int k0 = 0; k0 < 128; k0 += BK) {
#pragma unroll
    for (int c = 0; c < 16; c++) {
      int idx = c * 256 + t;
      int m = idx >> 5;
      int kk = idx & 31;
      int row = i0 + m;
      As[kk][m] = (row < M) ? ldv(A[(size_t)row * 128 + k0 + kk]) : 0.f;
    }
#pragma unroll
    for (int c = 0; c < 16; c++) {
      int idx = c * 256 + t;
      int o = idx & 127;
      int kk = idx >> 7;
      Bs[kk][o] = in_rd(W, (size_t)o * 128 + k0 + kk, fw);  // W is [out,in]
    }
    __syncthreads();
    int mrow = (t >> 4) * 8;
    int ncol = (t & 15) * 8;
#pragma unroll
    for (int kk = 0; kk < BK; kk++) {
      float a[8], b[8];
#pragma unroll
      for (int i = 0; i < 8; i++) a[i] = As[kk][mrow + i];
#pragma unroll
      for (int i = 0; i < 8; i++) b[i] = Bs[kk][ncol + i];
#pragma unroll
      for (int i = 0; i < 8; i++)
#pragma unroll
        for (int jx = 0; jx < 8; jx++) acc[i][jx] += a[i] * b[jx];
    }
    __syncthreads();
  }
  int mrow = (t >> 4) * 8;
  int ncol = (t & 15) * 8;
  float bv[8];
#pragma unroll
  for (int jx = 0; jx < 8; jx++) bv[jx] = in_rd(bias, ncol + jx, fb);
#pragma unroll
  for (int i = 0; i < 8; i++) {
    int row = i0 + mrow + i;
    if (row >= M) break;
#pragma unroll
    for (int jx = 0; jx < 8; jx++) {
      stv(&Out[(size_t)row * 128 + ncol + jx], lrelu(acc[i][jx] + bv[jx]));
    }
  }
}

// ---------------- fused RGCN conv: tiled GEMM with in-staging CSR mean-gather ----------
// Out = X @ root + mean0 @ rw[0] + mean1 @ rw[1] + bias   (root/rw in math [K,N] layout)
template <typename T>
__global__ __launch_bounds__(256, 2) void conv_gather_gemm(
    const T* __restrict__ X, const int* __restrict__ off, const int* __restrict__ cnt,
    const int* __restrict__ elist, const float* __restrict__ inv,
    const void* __restrict__ root, const void* __restrict__ rw,
    const void* __restrict__ bias, const int* __restrict__ fl, T* __restrict__ Out, int M) {
  const int fw = fl[17], fr = fl[16], fb = fl[18];
  __shared__ float As[BK][LDA];
  __shared__ float Bs[BK][LDA];
  int t = threadIdx.x;
  int i0 = blockIdx.x * 128;
  float acc[8][8] = {};
  for (int seg = 0; seg < 3; seg++) {
    for (int k0 = 0; k0 < 128; k0 += BK) {
      // ---- A staging (gathered mean for seg>0) ----
      int kk = t & 31;
      int m0 = t >> 5;
      for (int p = 0; p < 16; p++) {
        int m = p * 8 + m0;
        int row = i0 + m;
        float v = 0.f;
        if (row < M) {
          if (seg == 0) {
            v = ldv(X[(size_t)row * 128 + k0 + kk]);
          } else {
            int idx = (seg - 1) * M + row;
            int st = off[idx];
            int en = st + cnt[idx];
            float a = 0.f;
            for (int e = st; e < en; e++) {
              int src = elist[e];
              a += ldv(X[(size_t)src * 128 + k0 + kk]);
            }
            v = a * inv[idx];
          }
        }
        As[kk][m] = v;
      }
      // ---- B staging (math [K,N]) ----
#pragma unroll
      for (int c = 0; c < 16; c++) {
        int idx = c * 256 + t;
        int o = idx & 127;
        int k2 = idx >> 7;
        float bvv = (seg == 0)
                        ? in_rd(root, (size_t)(k0 + k2) * 128 + o, fw)
                        : in_rd(rw, (size_t)(seg - 1) * 16384 + (size_t)(k0 + k2) * 128 + o, fr);
        Bs[k2][o] = bvv;
      }
      __syncthreads();
      int mrow = (t >> 4) * 8;
      int ncol = (t & 15) * 8;
#pragma unroll
      for (int k2 = 0; k2 < BK; k2++) {
        float a[8], b[8];
#pragma unroll
        for (int i = 0; i < 8; i++) a[i] = As[k2][mrow + i];
#pragma unroll
        for (int i = 0; i < 8; i++) b[i] = Bs[k2][ncol + i];
#pragma unroll
        for (int i = 0; i < 8; i++)
#pragma unroll
          for (int jx = 0; jx < 8; jx++) acc[i][jx] += a[i] * b[jx];
      }
      __syncthreads();
    }
  }
  int mrow = (t >> 4) * 8;
  int ncol = (t & 15) * 8;
  float bv[8];
#pragma unroll
  for (int jx = 0; jx < 8; jx++) bv[jx] = in_rd(bias, ncol + jx, fb);
#pragma unroll
  for (int i = 0; i < 8; i++) {
    int row = i0 + mrow + i;
    if (row >= M) break;
#pragma unroll
    for (int jx = 0; jx < 8; jx++) {
      stv(&Out[(size_t)row * 128 + ncol + jx], acc[i][jx] + bv[jx]);
    }
  }
}

// ---------------- final 128 -> 2 linear, FP32 out ----------------
template <typename T>
__global__ void out_linear(const T* __restrict__ x, const void* __restrict__ W,
                           const void* __restrict__ B, const int* __restrict__ fl,
                           float* __restrict__ out, int NNr) {
  int wave = threadIdx.x >> 6;
  int lane = threadIdx.x & 63;
  int i = blockIdx.x * 4 + wave;
  if (i >= NNr) return;
  int fw = fl[21], fb = fl[22];
  const T* xr = x + (size_t)i * 128;
  float x0 = ldv(xr[lane]);
  float x1 = ldv(xr[lane + 64]);
  float p0 = x0 * in_rd(W, lane, fw) + x1 * in_rd(W, lane + 64, fw);
  float p1 = x0 * in_rd(W, 128 + lane, fw) + x1 * in_rd(W, 128 + lane + 64, fw);
#pragma unroll
  for (int offs = 32; offs; offs >>= 1) {
    p0 += __shfl_down(p0, offs, 64);
    p1 += __shfl_down(p1, offs, 64);
  }
  if (lane == 0) {
    out[(size_t)i * 2] = p0 + in_rd(B, 0, fb);
    out[(size_t)i * 2 + 1] = p1 + in_rd(B, 1, fb);
  }
}

// ---------------- pipeline ----------------
template <typename T>
static void run_pipeline(void* const* d_in, const int* S, float* out, char* ws,
                         int NUr, int NTr, int NEr, int dDes, int dNum, int dCat, int dTw,
                         hipStream_t stream) {
  const int NNr = NUr + NTr;
  const size_t xbytes = (size_t)NNr * 128 * sizeof(T);
  T* xa = (T*)ws;
  T* xb = (T*)(ws + xbytes);
  char* p = ws + 2 * xbytes;
  int* cnt = (int*)p;     p += (size_t)2 * NNr * 4;
  int* fill = (int*)p;    p += (size_t)2 * NNr * 4;  // contiguous with cnt
  int* off = (int*)p;     p += (size_t)2 * NNr * 4;
  int* bsum = (int*)p;    p += 2048 * 4;
  int* bsumsc = (int*)p;  p += 2048 * 4;
  float* inv = (float*)p; p += (size_t)2 * NNr * 4;
  int* elist = (int*)p;   p += (size_t)NEr * 4;
  int* flags = (int*)p;

  // per-array dtype detection
  const int fidx[20] = {0, 1, 2, 3, 6, 7, 8, 9, 10, 11, 12, 13, 14, 15, 16, 17, 18, 19, 20, 21};
  for (int q = 0; q < 20; q++) {
    int i = fidx[q];
    int s = S[i] / 2;
    if (s > 256) s = 256;
    if (s < 1) s = 1;
    detect_probe<<<1, 256, 0, stream>>>((const unsigned int*)d_in[i], s, 0, flags + i);
  }
  inherit_flag<<<1, 64, 0, stream>>>(flags, 22, 21);  // b_o2 inherits W_o2
  {
    int s = NEr < 256 ? NEr : 256;
    detect_probe<<<1, 256, 0, stream>>>((const unsigned int*)d_in[4], s, 1, flags + 4);
    int s2 = NEr / 2 < 256 ? NEr / 2 : 256;
    if (s2 < 1) s2 = 1;
    detect_probe<<<1, 256, 0, stream>>>((const unsigned int*)d_in[5], s2, 1, flags + 5);
  }

  const void* ei = d_in[4];
  const void* et = d_in[5];
  const int nb1 = (2 * NNr + 1023) / 1024;

  // CSR build (shared by both convs)
  zero_ints<<<(4 * NNr + 255) / 256, 256, 0, stream>>>(cnt, 4 * NNr);  // cnt + fill
  zero_ints<<<16, 256, 0, stream>>>(bsum, 4096);                       // bsum + bsumsc
  count_edges<<<(NEr + 255) / 256, 256, 0, stream>>>(ei, et, flags, cnt, NEr, NNr);
  scan_blocks<<<nb1, 256, 0, stream>>>(cnt, off, bsum, 2 * NNr);
  scan_blocks<<<1, 256, 0, stream>>>(bsum, bsumsc, nullptr, nb1);
  scan_add_inv<<<(2 * NNr + 255) / 256, 256, 0, stream>>>(off, bsumsc, cnt, inv, 2 * NNr);
  fill_elist<<<(NEr + 255) / 256, 256, 0, stream>>>(ei, et, flags, off, fill, elist, NEr, NNr);

  // encoders -> xa (tiled LDS-weight GEMMs)
  enc_gemm<T><<<(NUr + 63) / 64, 256, 0, stream>>>(d_in[0], d_in[6], d_in[7], flags, 0, 6, 7,
                                                   xa, NUr, dDes, 64, 0, 0);
  enc_gemm<T><<<(NUr + 63) / 64, 256, 0, stream>>>(d_in[2], d_in[8], d_in[9], flags, 2, 8, 9,
                                                   xa, NUr, dNum, 32, 0, 64);
  enc_gemm<T><<<(NUr + 63) / 64, 256, 0, stream>>>(d_in[3], d_in[10], d_in[11], flags, 3, 10,
                                                   11, xa, NUr, dCat, 32, 0, 96);
  enc_gemm<T><<<(NTr + 63) / 64, 256, 0, stream>>>(d_in[1], d_in[12], d_in[13], flags, 1, 12,
                                                   13, xa, NTr, dTw, 128, NUr, 0);

  const int mt = (NNr + 127) / 128;
  // x = lrelu(x @ W_in^T + b_in): xa -> xb
  gemm_k128<T><<<mt, 256, 0, stream>>>(xa, d_in[14], d_in[15], flags, 14, 15, xb, NNr);

  // conv1: xb -> xa ; conv2: xa -> xb
  conv_gather_gemm<T><<<mt, 256, 0, stream>>>(xb, off, cnt, elist, inv, d_in[17], d_in[16],
                                              d_in[18], flags, xa, NNr);
  conv_gather_gemm<T><<<mt, 256, 0, stream>>>(xa, off, cnt, elist, inv, d_in[17], d_in[16],
                                              d_in[18], flags, xb, NNr);

  // x = lrelu(x @ W_o1^T + b_o1): xb -> xa
  gemm_k128<T><<<mt, 256, 0, stream>>>(xb, d_in[19], d_in[20], flags, 19, 20, xa, NNr);

  // out = x @ W_o2^T + b_o2  (FP32 output)
  out_linear<T><<<(NNr + 3) / 4, 256, 0, stream>>>(xa, d_in[21], d_in[22], flags, out, NNr);
}

extern "C" void kernel_launch(void* const* d_in, const int* in_sizes, int n_in,
                              void* d_out, int out_size, void* d_ws, size_t ws_size,
                              hipStream_t stream) {
  float* out = (float*)d_out;
  char* ws = (char*)d_ws;

  auto signal = [&](int k) {
    sig_fill<<<(out_size + 255) / 256, 256, 0, stream>>>(out, out_size, (float)(200 + k));
  };

  if (n_in != 23) { signal(1); return; }
  const int* S = in_sizes;
  if (S[7] != 64 || S[9] != 32 || S[11] != 32 || S[13] != 128) { signal(2); return; }
  if (S[15] != 128) { signal(3); return; }
  if (S[6] % 64 || S[8] % 32 || S[10] % 32 || S[12] % 128) { signal(4); return; }
  int dDes = S[6] / 64, dNum = S[8] / 32, dCat = S[10] / 32, dTw = S[12] / 128;
  if (dDes <= 0 || dTw <= 0 || S[0] % dDes || S[1] % dTw) { signal(5); return; }
  if (dDes > 101 || dNum > 101 || dCat > 101 || dTw > 101) { signal(4); return; }
  int NUr = S[0] / dDes, NTr = S[1] / dTw, NNr = NUr + NTr, NEr = S[5];
  if (S[2] != NUr * dNum || S[3] != NUr * dCat) { signal(5); return; }
  if (S[4] != 2 * NEr || NEr < 1024) { signal(6); return; }
  if (S[14] != 16384 || S[16] != 32768 || S[17] != 16384 || S[18] != 128 ||
      S[19] != 16384 || S[20] != 128 || S[21] != 256 || S[22] != 2) { signal(7); return; }
  if (out_size != NNr * 2) { signal(8); return; }

  const size_t smallBytes =
      (size_t)4 * ((size_t)2 * NNr * 4) + 2 * 2048 * 4 + (size_t)NEr * 4 + 256;
  const size_t needF32 = 2 * (size_t)NNr * 128 * 4 + smallBytes;
  const size_t needB16 = 2 * (size_t)NNr * 128 * 2 + smallBytes;

  if (ws_size >= needF32) {
    run_pipeline<float>(d_in, S, out, ws, NUr, NTr, NEr, dDes, dNum, dCat, dTw, stream);
  } else if (ws_size >= needB16) {
    run_pipeline<bf16>(d_in, S, out, ws, NUr, NTr, NEr, dDes, dNum, dCat, dTw, stream);
  } else {
    signal(9);
  }
}

// Round 9
// 3416.268 us; speedup vs baseline: 5.7026x; 1.2122x over previous
//
#include <hip/hip_runtime.h>
#include <hip/hip_bf16.h>

typedef __hip_bfloat16 bf16;

#define BK 32
#define LDA 132  // padded LDS leading dim

__device__ __forceinline__ float lrelu(float x) { return x > 0.f ? x : 0.01f * x; }

__device__ __forceinline__ float ldv(float v) { return v; }
__device__ __forceinline__ float ldv(bf16 v) { return __bfloat162float(v); }
__device__ __forceinline__ void stv(float* p, float v) { *p = v; }
__device__ __forceinline__ void stv(bf16* p, float v) { *p = __float2bfloat16(v); }

__device__ __forceinline__ float in_rd(const void* p, size_t i, int isbf) {
  return isbf ? __bfloat162float(((const bf16*)p)[i]) : ((const float*)p)[i];
}
__device__ __forceinline__ int ix_rd(const void* p, size_t i, int is64) {
  return is64 ? (int)((const long long*)p)[i] : ((const int*)p)[i];
}

// ---------------- fused per-array format probe: one launch, 23 blocks ----------------
struct ProbeArgs {
  const void* p[23];
  int s[23];
  int mode[23];
};

__global__ void detect_all(ProbeArgs a, int* __restrict__ flags) {
  __shared__ int sh[256];
  int b = blockIdx.x;
  const unsigned int* w = (const unsigned int*)a.p[b];
  int s = a.s[b], mode = a.mode[b];
  int t = threadIdx.x;
  int c = 0;
  if (t < s) {
    if (mode == 0) {
      unsigned int v = w[t];
      int e = (v >> 7) & 0xFF;
      c = (e >= 100 && e <= 140) ? 1 : 0;
    } else {
      c = (w[2 * t + 1] == 0u) ? 1 : 0;
    }
  }
  sh[t] = c;
  __syncthreads();
  for (int d = 128; d; d >>= 1) {
    if (t < d) sh[t] += sh[t + d];
    __syncthreads();
  }
  if (t == 0) flags[b] = (mode == 0) ? (sh[0] * 10 >= 7 * s) : (sh[0] * 10 >= 9 * s);
}

// ---------------- weight prep: fp32 (+transpose for torch-layout) into workspace ------
// layout (floats): [0,16384) W_inT [k,n]; [16384,32768) W_o1T [k,n]; [32768,49152) root;
// [49152,81920) rw; [81920] b_in; [82048] rgcn_bias; [82176] b_o1; [82304] W_o2; [82560] b_o2
#define PW_TOTAL 82562
__global__ void prep_weights(const void* Win, const void* bin, const void* rw,
                             const void* root, const void* rb, const void* Wo1,
                             const void* bo1, const void* Wo2, const void* bo2,
                             const int* __restrict__ fl, float* __restrict__ pw) {
  int i = blockIdx.x * 256 + threadIdx.x;
  if (i >= PW_TOTAL) return;
  if (i < 16384) {
    int k = i >> 7, o = i & 127;
    pw[i] = in_rd(Win, (size_t)o * 128 + k, fl[14]);
  } else if (i < 32768) {
    int j = i - 16384;
    int k = j >> 7, o = j & 127;
    pw[i] = in_rd(Wo1, (size_t)o * 128 + k, fl[19]);
  } else if (i < 49152) {
    pw[i] = in_rd(root, i - 32768, fl[17]);
  } else if (i < 81920) {
    pw[i] = in_rd(rw, i - 49152, fl[16]);
  } else if (i < 82048) {
    pw[i] = in_rd(bin, i - 81920, fl[15]);
  } else if (i < 82176) {
    pw[i] = in_rd(rb, i - 82048, fl[18]);
  } else if (i < 82304) {
    pw[i] = in_rd(bo1, i - 82176, fl[20]);
  } else if (i < 82560) {
    pw[i] = in_rd(Wo2, i - 82304, fl[21]);
  } else {
    pw[i] = in_rd(bo2, i - 82560, fl[22]);
  }
}

// ---------------- utilities ----------------
__global__ void sig_fill(float* __restrict__ p, int n, float v) {
  int i = blockIdx.x * 256 + threadIdx.x;
  if (i < n) p[i] = v;
}
__global__ void zero_ints(int* __restrict__ p, int n) {
  int i = blockIdx.x * 256 + threadIdx.x;
  if (i < n) p[i] = 0;
}

// ---------------- CSR build ----------------
__global__ void count_edges(const void* __restrict__ ei, const void* __restrict__ et,
                            const int* __restrict__ fl, int* __restrict__ cnt, int NEr,
                            int NNr) {
  int e = blockIdx.x * 256 + threadIdx.x;
  if (e >= NEr) return;
  int d = ix_rd(ei, (size_t)NEr + e, fl[4]);
  int r = ix_rd(et, e, fl[5]) & 1;
  if ((unsigned)d >= (unsigned)NNr) return;
  atomicAdd(&cnt[r * NNr + d], 1);
}

__global__ void scan_blocks(const int* __restrict__ in, int* __restrict__ out,
                            int* __restrict__ bsum, int n) {
  __shared__ int sh[256];
  int t = threadIdx.x;
  int base = blockIdx.x * 1024 + t * 4;
  int a[4];
  int s = 0;
#pragma unroll
  for (int i = 0; i < 4; i++) {
    a[i] = (base + i < n) ? in[base + i] : 0;
    s += a[i];
  }
  sh[t] = s;
  __syncthreads();
  for (int d = 1; d < 256; d <<= 1) {
    int v = (t >= d) ? sh[t - d] : 0;
    __syncthreads();
    sh[t] += v;
    __syncthreads();
  }
  int ex = sh[t] - s;
#pragma unroll
  for (int i = 0; i < 4; i++) {
    if (base + i < n) out[base + i] = ex;
    ex += a[i];
  }
  if (t == 255 && bsum) bsum[blockIdx.x] = sh[255];
}

__global__ void scan_add_inv(int* __restrict__ off, const int* __restrict__ bsumsc,
                             const int* __restrict__ cnt, float* __restrict__ inv, int n) {
  int i = blockIdx.x * 256 + threadIdx.x;
  if (i >= n) return;
  off[i] += bsumsc[i >> 10];
  inv[i] = 1.f / fmaxf((float)cnt[i], 1.f);
}

__global__ void fill_elist(const void* __restrict__ ei, const void* __restrict__ et,
                           const int* __restrict__ fl, const int* __restrict__ off,
                           int* __restrict__ fill, int* __restrict__ elist, int NEr, int NNr) {
  int e = blockIdx.x * 256 + threadIdx.x;
  if (e >= NEr) return;
  int s = ix_rd(ei, e, fl[4]);
  int d = ix_rd(ei, (size_t)NEr + e, fl[4]);
  int r = ix_rd(et, e, fl[5]) & 1;
  if ((unsigned)d >= (unsigned)NNr || (unsigned)s >= (unsigned)NNr) return;
  int idx = r * NNr + d;
  int slot = off[idx] + atomicAdd(&fill[idx], 1);
  elist[slot] = s;
}

// ---------------- encoder GEMM (unchanged from R8) ----------------
template <typename T>
__global__ __launch_bounds__(256) void enc_gemm(const void* __restrict__ A,
                                                const void* __restrict__ W,
                                                const void* __restrict__ B,
                                                const int* __restrict__ fl, int fa, int fw,
                                                int fb, T* __restrict__ x, int M, int K, int N,
                                                int row0, int col0) {
  __shared__ float Wb[128 * 102];
  __shared__ float bb[128];
  int t = threadIdx.x;
  int stride = (K & 1) ? K : K + 1;
  int fA = fl[fa];
  {
    int fW = fl[fw], fB = fl[fb];
    for (int idx = t; idx < N * K; idx += 256) {
      int j = idx / K, k = idx - j * K;
      Wb[j * stride + k] = in_rd(W, (size_t)j * K + k, fW);
    }
    if (t < N) bb[t] = in_rd(B, t, fB);
  }
  __syncthreads();
  int j = t % N;
  int r = t / N;
  int R = 256 / N;
  int iEnd = blockIdx.x * 64 + 64;
  if (iEnd > M) iEnd = M;
  const float* wrow = &Wb[j * stride];
  if (!fA) {
    const float* Af = (const float*)A;
    for (int i = blockIdx.x * 64 + r; i < iEnd; i += R) {
      const float* a = Af + (size_t)i * K;
      float acc = bb[j];
      for (int k = 0; k < K; k++) acc += a[k] * wrow[k];
      stv(&x[(size_t)(row0 + i) * 128 + col0 + j], lrelu(acc));
    }
  } else {
    const bf16* Ab = (const bf16*)A;
    for (int i = blockIdx.x * 64 + r; i < iEnd; i += R) {
      const bf16* a = Ab + (size_t)i * K;
      float acc = bb[j];
      for (int k = 0; k < K; k++) acc += __bfloat162float(a[k]) * wrow[k];
      stv(&x[(size_t)(row0 + i) * 128 + col0 + j], lrelu(acc));
    }
  }
}

// ---------------- gather means: 1 block = 1 node, 2 rels x 128 cols ----------------
template <typename T>
__global__ __launch_bounds__(256) void gather_means(const T* __restrict__ X,
                                                    const int* __restrict__ off,
                                                    const int* __restrict__ cnt,
                                                    const int* __restrict__ elist,
                                                    const float* __restrict__ inv,
                                                    bf16* __restrict__ mean, int NNr) {
  int node = blockIdx.x;
  int rel = threadIdx.x >> 7;
  int col = threadIdx.x & 127;
  int idx = rel * NNr + node;
  int st = off[idx];
  int n = cnt[idx];
  float s = 0.f;
  for (int e = 0; e < n; e++) {
    int src = elist[st + e];
    s += ldv(X[(size_t)src * 128 + col]);  // coalesced across 128 lanes
  }
  mean[(size_t)rel * NNr * 128 + (size_t)node * 128 + col] = __float2bfloat16(s * inv[idx]);
}

// ---------------- tiled K=128 GEMM, prepped [K,N] fp32 weight, +bias, lrelu ----------
// split-4 register tile: rows mrow4+{0..3,64..67}, cols ncol4+{0..3,64..67} -> all LDS
// reads broadcast or 2-way (free). A-staging writes keep a 4-way (small volume).
template <typename T>
__global__ __launch_bounds__(256, 2) void gemm_k128(const T* __restrict__ A,
                                                    const float* __restrict__ Wt,
                                                    const float* __restrict__ bias,
                                                    T* __restrict__ Out, int M) {
  __shared__ __align__(16) float As[BK][LDA];
  __shared__ __align__(16) float Bs[BK][LDA];
  int t = threadIdx.x;
  int i0 = blockIdx.x * 128;
  int mrow4 = (t >> 4) * 4;
  int ncol4 = (t & 15) * 4;
  float acc[8][8] = {};
  for (int k0 = 0; k0 < 128; k0 += BK) {
#pragma unroll
    for (int c = 0; c < 16; c++) {
      int idx = c * 256 + t;
      int m = idx >> 5;
      int kk = idx & 31;
      int row = i0 + m;
      As[kk][m] = (row < M) ? ldv(A[(size_t)row * 128 + k0 + kk]) : 0.f;
    }
#pragma unroll
    for (int c = 0; c < 16; c++) {
      int idx = c * 256 + t;
      int o = idx & 127;
      int kk = idx >> 7;
      Bs[kk][o] = Wt[(size_t)(k0 + kk) * 128 + o];  // coalesced, stride-1 LDS write
    }
    __syncthreads();
#pragma unroll
    for (int k2 = 0; k2 < BK; k2++) {
      float4 a0 = *(const float4*)&As[k2][mrow4];
      float4 a1 = *(const float4*)&As[k2][mrow4 + 64];
      float4 b0 = *(const float4*)&Bs[k2][ncol4];
      float4 b1 = *(const float4*)&Bs[k2][ncol4 + 64];
      float av[8] = {a0.x, a0.y, a0.z, a0.w, a1.x, a1.y, a1.z, a1.w};
      float bv[8] = {b0.x, b0.y, b0.z, b0.w, b1.x, b1.y, b1.z, b1.w};
#pragma unroll
      for (int i = 0; i < 8; i++)
#pragma unroll
        for (int j = 0; j < 8; j++) acc[i][j] += av[i] * bv[j];
    }
    __syncthreads();
  }
  float bvv[8];
#pragma unroll
  for (int j = 0; j < 8; j++) bvv[j] = bias[ncol4 + (j < 4 ? j : 60 + j)];
#pragma unroll
  for (int i = 0; i < 8; i++) {
    int row = i0 + mrow4 + (i < 4 ? i : 60 + i);
    if (row < M) {
#pragma unroll
      for (int j = 0; j < 8; j++) {
        int col = ncol4 + (j < 4 ? j : 60 + j);
        stv(&Out[(size_t)row * 128 + col], lrelu(acc[i][j] + bvv[j]));
      }
    }
  }
}

// ---------------- RGCN conv GEMM: PRE=true uses precomputed bf16 means; else fused gather
template <typename T, bool PRE>
__global__ __launch_bounds__(256, 2) void conv_gemm(
    const T* __restrict__ X, const bf16* __restrict__ mean, const int* __restrict__ off,
    const int* __restrict__ cnt, const int* __restrict__ elist, const float* __restrict__ inv,
    const float* __restrict__ root, const float* __restrict__ rw,
    const float* __restrict__ bias, T* __restrict__ Out, int M) {
  __shared__ __align__(16) float As[BK][LDA];
  __shared__ __align__(16) float Bs[BK][LDA];
  int t = threadIdx.x;
  int i0 = blockIdx.x * 128;
  int mrow4 = (t >> 4) * 4;
  int ncol4 = (t & 15) * 4;
  float acc[8][8] = {};
  for (int seg = 0; seg < 3; seg++) {
    const float* B = (seg == 0) ? root : rw + (size_t)(seg - 1) * 16384;
    for (int k0 = 0; k0 < 128; k0 += BK) {
      if (PRE) {
#pragma unroll
        for (int c = 0; c < 16; c++) {
          int idx = c * 256 + t;
          int m = idx >> 5;
          int kk = idx & 31;
          int row = i0 + m;
          float v = 0.f;
          if (row < M) {
            v = (seg == 0) ? ldv(X[(size_t)row * 128 + k0 + kk])
                           : __bfloat162float(
                                 mean[(size_t)(seg - 1) * M * 128 + (size_t)row * 128 + k0 + kk]);
          }
          As[kk][m] = v;
        }
      } else {
        int kk = t & 31;
        int m0 = t >> 5;
        for (int p = 0; p < 16; p++) {
          int m = p * 8 + m0;
          int row = i0 + m;
          float v = 0.f;
          if (row < M) {
            if (seg == 0) {
              v = ldv(X[(size_t)row * 128 + k0 + kk]);
            } else {
              int idx = (seg - 1) * M + row;
              int st = off[idx];
              int en = st + cnt[idx];
              float a = 0.f;
              for (int e = st; e < en; e++) a += ldv(X[(size_t)elist[e] * 128 + k0 + kk]);
              v = a * inv[idx];
            }
          }
          As[kk][m] = v;
        }
      }
#pragma unroll
      for (int c = 0; c < 16; c++) {
        int idx = c * 256 + t;
        int o = idx & 127;
        int k2 = idx >> 7;
        Bs[k2][o] = B[(size_t)(k0 + k2) * 128 + o];
      }
      __syncthreads();
#pragma unroll
      for (int k2 = 0; k2 < BK; k2++) {
        float4 a0 = *(const float4*)&As[k2][mrow4];
        float4 a1 = *(const float4*)&As[k2][mrow4 + 64];
        float4 b0 = *(const float4*)&Bs[k2][ncol4];
        float4 b1 = *(const float4*)&Bs[k2][ncol4 + 64];
        float av[8] = {a0.x, a0.y, a0.z, a0.w, a1.x, a1.y, a1.z, a1.w};
        float bv[8] = {b0.x, b0.y, b0.z, b0.w, b1.x, b1.y, b1.z, b1.w};
#pragma unroll
        for (int i = 0; i < 8; i++)
#pragma unroll
          for (int j = 0; j < 8; j++) acc[i][j] += av[i] * bv[j];
      }
      __syncthreads();
    }
  }
  float bvv[8];
#pragma unroll
  for (int j = 0; j < 8; j++) bvv[j] = bias[ncol4 + (j < 4 ? j : 60 + j)];
#pragma unroll
  for (int i = 0; i < 8; i++) {
    int row = i0 + mrow4 + (i < 4 ? i : 60 + i);
    if (row < M) {
#pragma unroll
      for (int j = 0; j < 8; j++) {
        int col = ncol4 + (j < 4 ? j : 60 + j);
        stv(&Out[(size_t)row * 128 + col], acc[i][j] + bvv[j]);
      }
    }
  }
}

// ---------------- final 128 -> 2 linear, FP32 out ----------------
template <typename T>
__global__ void out_linear(const T* __restrict__ x, const float* __restrict__ W,
                           const float* __restrict__ B, float* __restrict__ out, int NNr) {
  int wave = threadIdx.x >> 6;
  int lane = threadIdx.x & 63;
  int i = blockIdx.x * 4 + wave;
  if (i >= NNr) return;
  const T* xr = x + (size_t)i * 128;
  float x0 = ldv(xr[lane]);
  float x1 = ldv(xr[lane + 64]);
  float p0 = x0 * W[lane] + x1 * W[lane + 64];
  float p1 = x0 * W[128 + lane] + x1 * W[128 + lane + 64];
#pragma unroll
  for (int offs = 32; offs; offs >>= 1) {
    p0 += __shfl_down(p0, offs, 64);
    p1 += __shfl_down(p1, offs, 64);
  }
  if (lane == 0) {
    out[(size_t)i * 2] = p0 + B[0];
    out[(size_t)i * 2 + 1] = p1 + B[1];
  }
}

// ---------------- pipeline ----------------
template <typename T>
static void run_pipeline(void* const* d_in, const int* S, float* out, char* ws,
                         size_t ws_size, int NUr, int NTr, int NEr, int dDes, int dNum,
                         int dCat, int dTw, hipStream_t stream) {
  const int NNr = NUr + NTr;
  const size_t xbytes = (size_t)NNr * 128 * sizeof(T);
  const size_t mbytes = (size_t)2 * NNr * 128 * sizeof(bf16);
  const size_t smallBytes = (size_t)4 * ((size_t)2 * NNr * 4) + 2 * 2048 * 4 +
                            (size_t)NEr * 4 + (size_t)PW_TOTAL * 4 + 512;
  const bool pre = (sizeof(T) == 4) && (ws_size >= 2 * xbytes + mbytes + smallBytes);

  T* xa = (T*)ws;
  T* xb = (T*)(ws + xbytes);
  bf16* means = (bf16*)(ws + 2 * xbytes);
  char* p = ws + 2 * xbytes + (pre ? mbytes : 0);
  int* cnt = (int*)p;      p += (size_t)2 * NNr * 4;
  int* fill = (int*)p;     p += (size_t)2 * NNr * 4;  // contiguous with cnt
  int* off = (int*)p;      p += (size_t)2 * NNr * 4;
  int* bsum = (int*)p;     p += 2048 * 4;             // contiguous with bsumsc
  int* bsumsc = (int*)p;   p += 2048 * 4;
  float* inv = (float*)p;  p += (size_t)2 * NNr * 4;
  int* elist = (int*)p;    p += (size_t)NEr * 4;
  float* pw = (float*)p;   p += (size_t)PW_TOTAL * 4;
  int* flags = (int*)p;

  // ---- format probes: one launch ----
  ProbeArgs pa;
  for (int i = 0; i < 23; i++) {
    int src = (i == 22) ? 21 : i;  // b_o2 (2 elems) inherits W_o2's dtype
    pa.p[i] = d_in[src];
    if (i == 4) {
      pa.mode[i] = 1;
      pa.s[i] = NEr < 256 ? NEr : 256;
    } else if (i == 5) {
      pa.mode[i] = 1;
      int s2 = NEr / 2 < 256 ? NEr / 2 : 256;
      pa.s[i] = s2 < 1 ? 1 : s2;
    } else {
      pa.mode[i] = 0;
      int s = S[src] / 2;
      if (s > 256) s = 256;
      if (s < 1) s = 1;
      pa.s[i] = s;
    }
  }
  detect_all<<<23, 256, 0, stream>>>(pa, flags);
  prep_weights<<<(PW_TOTAL + 255) / 256, 256, 0, stream>>>(
      d_in[14], d_in[15], d_in[16], d_in[17], d_in[18], d_in[19], d_in[20], d_in[21],
      d_in[22], flags, pw);

  const float* WtIn = pw;
  const float* WtO1 = pw + 16384;
  const float* rootp = pw + 32768;
  const float* rwp = pw + 49152;
  const float* bIn = pw + 81920;
  const float* rbp = pw + 82048;
  const float* bO1 = pw + 82176;
  const float* Wo2p = pw + 82304;
  const float* bo2p = pw + 82560;

  const void* ei = d_in[4];
  const void* et = d_in[5];
  const int nb1 = (2 * NNr + 1023) / 1024;

  // ---- CSR build ----
  zero_ints<<<(4 * NNr + 255) / 256, 256, 0, stream>>>(cnt, 4 * NNr);
  zero_ints<<<16, 256, 0, stream>>>(bsum, 4096);
  count_edges<<<(NEr + 255) / 256, 256, 0, stream>>>(ei, et, flags, cnt, NEr, NNr);
  scan_blocks<<<nb1, 256, 0, stream>>>(cnt, off, bsum, 2 * NNr);
  scan_blocks<<<1, 256, 0, stream>>>(bsum, bsumsc, nullptr, nb1);
  scan_add_inv<<<(2 * NNr + 255) / 256, 256, 0, stream>>>(off, bsumsc, cnt, inv, 2 * NNr);
  fill_elist<<<(NEr + 255) / 256, 256, 0, stream>>>(ei, et, flags, off, fill, elist, NEr, NNr);

  // ---- encoders -> xa ----
  enc_gemm<T><<<(NUr + 63) / 64, 256, 0, stream>>>(d_in[0], d_in[6], d_in[7], flags, 0, 6, 7,
                                                   xa, NUr, dDes, 64, 0, 0);
  enc_gemm<T><<<(NUr + 63) / 64, 256, 0, stream>>>(d_in[2], d_in[8], d_in[9], flags, 2, 8, 9,
                                                   xa, NUr, dNum, 32, 0, 64);
  enc_gemm<T><<<(NUr + 63) / 64, 256, 0, stream>>>(d_in[3], d_in[10], d_in[11], flags, 3, 10,
                                                   11, xa, NUr, dCat, 32, 0, 96);
  enc_gemm<T><<<(NTr + 63) / 64, 256, 0, stream>>>(d_in[1], d_in[12], d_in[13], flags, 1, 12,
                                                   13, xa, NTr, dTw, 128, NUr, 0);

  const int mt = (NNr + 127) / 128;
  gemm_k128<T><<<mt, 256, 0, stream>>>(xa, WtIn, bIn, xb, NNr);

  if (pre) {
    gather_means<T><<<NNr, 256, 0, stream>>>(xb, off, cnt, elist, inv, means, NNr);
    conv_gemm<T, true><<<mt, 256, 0, stream>>>(xb, means, off, cnt, elist, inv, rootp, rwp,
                                               rbp, xa, NNr);
    gather_means<T><<<NNr, 256, 0, stream>>>(xa, off, cnt, elist, inv, means, NNr);
    conv_gemm<T, true><<<mt, 256, 0, stream>>>(xa, means, off, cnt, elist, inv, rootp, rwp,
                                               rbp, xb, NNr);
  } else {
    conv_gemm<T, false><<<mt, 256, 0, stream>>>(xb, nullptr, off, cnt, elist, inv, rootp, rwp,
                                                rbp, xa, NNr);
    conv_gemm<T, false><<<mt, 256, 0, stream>>>(xa, nullptr, off, cnt, elist, inv, rootp, rwp,
                                                rbp, xb, NNr);
  }

  gemm_k128<T><<<mt, 256, 0, stream>>>(xb, WtO1, bO1, xa, NNr);
  out_linear<T><<<(NNr + 3) / 4, 256, 0, stream>>>(xa, Wo2p, bo2p, out, NNr);
}

extern "C" void kernel_launch(void* const* d_in, const int* in_sizes, int n_in,
                              void* d_out, int out_size, void* d_ws, size_t ws_size,
                              hipStream_t stream) {
  float* out = (float*)d_out;
  char* ws = (char*)d_ws;

  auto signal = [&](int k) {
    sig_fill<<<(out_size + 255) / 256, 256, 0, stream>>>(out, out_size, (float)(200 + k));
  };

  if (n_in != 23) { signal(1); return; }
  const int* S = in_sizes;
  if (S[7] != 64 || S[9] != 32 || S[11] != 32 || S[13] != 128) { signal(2); return; }
  if (S[15] != 128) { signal(3); return; }
  if (S[6] % 64 || S[8] % 32 || S[10] % 32 || S[12] % 128) { signal(4); return; }
  int dDes = S[6] / 64, dNum = S[8] / 32, dCat = S[10] / 32, dTw = S[12] / 128;
  if (dDes <= 0 || dTw <= 0 || S[0] % dDes || S[1] % dTw) { signal(5); return; }
  if (dDes > 101 || dNum > 101 || dCat > 101 || dTw > 101) { signal(4); return; }
  int NUr = S[0] / dDes, NTr = S[1] / dTw, NNr = NUr + NTr, NEr = S[5];
  if (S[2] != NUr * dNum || S[3] != NUr * dCat) { signal(5); return; }
  if (S[4] != 2 * NEr || NEr < 1024) { signal(6); return; }
  if (S[14] != 16384 || S[16] != 32768 || S[17] != 16384 || S[18] != 128 ||
      S[19] != 16384 || S[20] != 128 || S[21] != 256 || S[22] != 2) { signal(7); return; }
  if (out_size != NNr * 2) { signal(8); return; }

  const size_t smallBytes = (size_t)4 * ((size_t)2 * NNr * 4) + 2 * 2048 * 4 +
                            (size_t)NEr * 4 + (size_t)PW_TOTAL * 4 + 512;
  const size_t needF32 = 2 * (size_t)NNr * 128 * 4 + smallBytes;
  const size_t needB16 = 2 * (size_t)NNr * 128 * 2 + smallBytes;

  if (ws_size >= needF32) {
    run_pipeline<float>(d_in, S, out, ws, ws_size, NUr, NTr, NEr, dDes, dNum, dCat, dTw,
                        stream);
  } else if (ws_size >= needB16) {
    run_pipeline<bf16>(d_in, S, out, ws, ws_size, NUr, NTr, NEr, dDes, dNum, dCat, dTw,
                       stream);
  } else {
    signal(9);
  }
}